// Round 1
// baseline (1050.408 us; speedup 1.0000x reference)
//
#include <hip/hip_runtime.h>
#include <hip/hip_bf16.h>
#include <stdint.h>

#define NN 131072

// ---------------- ws layout (bytes) ----------------
// [0,            512K)  sim           (NN f32... wait, NN*4 = 512KB exactly)
// [512K,         1M  )  W_vf          (512*256 f32 = 512KB)
// [1M,           +1K )  c_f           (256 f32)
// 1M+1024              flag (int)
// 1M+2048              scale (256 f32)
// 1M+3072              shift (256 f32)
// [2M,           4M  )  bn_s          (2048*256 f32)
// [4M,           6M  )  bn_q          (2048*256 f32)
// [8M,           8M+128M) graph_feats (NN*256 f32)

__device__ __forceinline__ bool mask_val(const unsigned char* m8, int flag, int i) {
    return flag ? (m8[(size_t)i * 4] != 0) : (m8[i] != 0);
}

// Detect whether mask buffer is 1-byte bool (flag=0) or int32 (flag=1).
__global__ void k_detect(const unsigned char* m8, int n, int* flag) {
    __shared__ int cnt;
    if (threadIdx.x == 0) cnt = 0;
    __syncthreads();
    int local = 0;
    for (int i = threadIdx.x * 4 + 1; i < n; i += 1024) local += (m8[i] != 0) ? 1 : 0;
    if (local) atomicAdd(&cnt, local);
    __syncthreads();
    if (threadIdx.x == 0) *flag = (cnt == 0) ? 1 : 0;
}

// Fold W_vf = W_v @ W_f_bot  and  c_f = b_f + b_v @ W_f_bot
__global__ void k_fold(const float* __restrict__ Wv, const float* __restrict__ Wf,
                       const float* __restrict__ bv, const float* __restrict__ bf,
                       float* __restrict__ Wvf, float* __restrict__ cf) {
    int c = threadIdx.x;
    int b = blockIdx.x;
    if (b < 512) {
        const float* wrow = Wv + b * 256;
        float acc = 0.f;
        for (int j = 0; j < 256; ++j) acc += wrow[j] * Wf[(256 + j) * 256 + c];
        Wvf[b * 256 + c] = acc;
    } else {
        float acc = bf[c];
        for (int j = 0; j < 256; ++j) acc += bv[j] * Wf[(256 + j) * 256 + c];
        cf[c] = acc;
    }
}

// Cosine similarity per row: one wave per row, 4 rows per block.
__global__ void k_sim(const float* __restrict__ x, float* __restrict__ sim) {
    int wid = threadIdx.x >> 6;
    int lane = threadIdx.x & 63;
    int i = blockIdx.x * 4 + wid;
    const float4* a = (const float4*)(x + (size_t)i * 2048 + 1024);  // x[i,2,:]
    const float4* v = (const float4*)(x + (size_t)i * 2048 + 1536);  // x[i,3,:]
    float4 a0 = a[lane], a1 = a[lane + 64];
    float4 v0 = v[lane], v1 = v[lane + 64];
    float dot = a0.x * v0.x + a0.y * v0.y + a0.z * v0.z + a0.w * v0.w
              + a1.x * v1.x + a1.y * v1.y + a1.z * v1.z + a1.w * v1.w;
    float na = a0.x * a0.x + a0.y * a0.y + a0.z * a0.z + a0.w * a0.w
             + a1.x * a1.x + a1.y * a1.y + a1.z * a1.z + a1.w * a1.w;
    float nv = v0.x * v0.x + v0.y * v0.y + v0.z * v0.z + v0.w * v0.w
             + v1.x * v1.x + v1.y * v1.y + v1.z * v1.z + v1.w * v1.w;
    #pragma unroll
    for (int off = 32; off; off >>= 1) {
        dot += __shfl_xor(dot, off);
        na  += __shfl_xor(na,  off);
        nv  += __shfl_xor(nv,  off);
    }
    if (lane == 0) {
        float denom = fmaxf(sqrtf(na) * sqrtf(nv), 1e-8f);
        sim[i] = dot / denom;
    }
}

// Fused GEMM: graph_feats[i][c] = z(i) @ Bcat + bias(i), K=1024 virtual.
// BM=64 rows, BN=128 cols per block. Also writes BN partial sums.
__global__ __launch_bounds__(256) void k_gemm(
    const float* __restrict__ x, const unsigned char* __restrict__ m8,
    const int* __restrict__ flagp,
    const float* __restrict__ Wa, const float* __restrict__ Wf,
    const float* __restrict__ Wvf,
    const float* __restrict__ ba, const float* __restrict__ cf,
    const float* __restrict__ sim,
    float* __restrict__ gf, float* __restrict__ bn_s, float* __restrict__ bn_q)
{
    __shared__ float As[64][36];   // padded stride 36 (16B-aligned, bank-spread)
    __shared__ float Bs[32][128];

    int flag = *flagp;
    int bm = blockIdx.x;             // 0..2047
    int cBase = blockIdx.y * 128;    // 0 or 128
    int tid = threadIdx.x;
    int tx = tid & 15, ty = tid >> 4;
    int rowBase = bm * 64;

    // A-load assignment: 4 threads per row, 8 floats each
    int ar = tid >> 2;               // 0..63
    int ak = (tid & 3) * 8;          // 0,8,16,24
    int gi = rowBase + ar;
    bool m_ar = mask_val(m8, flag, gi);
    float simv = sim[gi];
    const float* xrow = x + (size_t)gi * 2048;

    // B-load assignment: 8 threads per row, 16 floats each
    int bk = tid >> 3;               // 0..31
    int bc = (tid & 7) * 16;

    float acc[4][8];
    #pragma unroll
    for (int q = 0; q < 4; ++q)
        #pragma unroll
        for (int j = 0; j < 8; ++j) acc[q][j] = 0.f;

    for (int k0 = 0; k0 < 1024; k0 += 32) {
        // ---- stage A tile (on-the-fly z construction) ----
        const float* src;
        float sc;
        if (k0 < 256)      { src = xrow + k0 + ak;              sc = m_ar ? 1.f : 0.f; }
        else if (k0 < 512) { src = xrow + (k0 - 256) + ak;      sc = m_ar ? 0.f : simv; }
        else               { src = xrow + 512 + (k0 - 512) + ak; sc = m_ar ? 0.f : 1.f; }
        const float4* p = (const float4*)src;
        float4 u0 = p[0], u1 = p[1];
        u0.x *= sc; u0.y *= sc; u0.z *= sc; u0.w *= sc;
        u1.x *= sc; u1.y *= sc; u1.z *= sc; u1.w *= sc;
        *(float4*)&As[ar][ak]     = u0;
        *(float4*)&As[ar][ak + 4] = u1;

        // ---- stage B tile ----
        int gk = k0 + bk;
        const float* Brow;
        if (gk < 256)      Brow = Wa + gk * 256;
        else if (gk < 512) Brow = Wf + (gk - 256) * 256;
        else               Brow = Wvf + (gk - 512) * 256;
        const float4* bp = (const float4*)(Brow + cBase + bc);
        float4 b0 = bp[0], b1 = bp[1], b2 = bp[2], b3 = bp[3];
        *(float4*)&Bs[bk][bc]      = b0;
        *(float4*)&Bs[bk][bc + 4]  = b1;
        *(float4*)&Bs[bk][bc + 8]  = b2;
        *(float4*)&Bs[bk][bc + 12] = b3;
        __syncthreads();

        // ---- compute ----
        #pragma unroll
        for (int kk = 0; kk < 32; ++kk) {
            float a0 = As[ty * 4 + 0][kk];
            float a1 = As[ty * 4 + 1][kk];
            float a2 = As[ty * 4 + 2][kk];
            float a3 = As[ty * 4 + 3][kk];
            float4 bb0 = *(const float4*)&Bs[kk][tx * 8];
            float4 bb1 = *(const float4*)&Bs[kk][tx * 8 + 4];
            float bvv[8] = {bb0.x, bb0.y, bb0.z, bb0.w, bb1.x, bb1.y, bb1.z, bb1.w};
            #pragma unroll
            for (int j = 0; j < 8; ++j) {
                acc[0][j] = fmaf(a0, bvv[j], acc[0][j]);
                acc[1][j] = fmaf(a1, bvv[j], acc[1][j]);
                acc[2][j] = fmaf(a2, bvv[j], acc[2][j]);
                acc[3][j] = fmaf(a3, bvv[j], acc[3][j]);
            }
        }
        __syncthreads();
    }

    // ---- epilogue: bias, store gf, BN partials ----
    float4 ba0 = *(const float4*)(ba + cBase + tx * 8);
    float4 ba1 = *(const float4*)(ba + cBase + tx * 8 + 4);
    float4 cf0 = *(const float4*)(cf + cBase + tx * 8);
    float4 cf1 = *(const float4*)(cf + cBase + tx * 8 + 4);

    float psum[8], psq[8];
    #pragma unroll
    for (int j = 0; j < 8; ++j) { psum[j] = 0.f; psq[j] = 0.f; }

    #pragma unroll
    for (int q = 0; q < 4; ++q) {
        int i = rowBase + ty * 4 + q;
        bool m = mask_val(m8, flag, i);
        float bias[8];
        bias[0] = m ? ba0.x : cf0.x; bias[1] = m ? ba0.y : cf0.y;
        bias[2] = m ? ba0.z : cf0.z; bias[3] = m ? ba0.w : cf0.w;
        bias[4] = m ? ba1.x : cf1.x; bias[5] = m ? ba1.y : cf1.y;
        bias[6] = m ? ba1.z : cf1.z; bias[7] = m ? ba1.w : cf1.w;
        float g[8];
        #pragma unroll
        for (int j = 0; j < 8; ++j) {
            g[j] = acc[q][j] + bias[j];
            psum[j] += g[j];
            psq[j]  += g[j] * g[j];
        }
        float4 o0 = {g[0], g[1], g[2], g[3]};
        float4 o1 = {g[4], g[5], g[6], g[7]};
        *(float4*)&gf[(size_t)i * 256 + cBase + tx * 8]     = o0;
        *(float4*)&gf[(size_t)i * 256 + cBase + tx * 8 + 4] = o1;
    }

    // reduce over ty (16 groups of 4 rows) via LDS reuse
    float* lsum = (float*)As;   // 2304 floats available, need 2048
    float* lsq  = (float*)Bs;   // 4096 floats available
    #pragma unroll
    for (int j = 0; j < 8; ++j) {
        lsum[ty * 128 + tx * 8 + j] = psum[j];
        lsq [ty * 128 + tx * 8 + j] = psq[j];
    }
    __syncthreads();
    if (tid < 128) {
        float s = 0.f, qq = 0.f;
        #pragma unroll
        for (int t = 0; t < 16; ++t) {
            s  += lsum[t * 128 + tid];
            qq += lsq [t * 128 + tid];
        }
        bn_s[(size_t)bm * 256 + cBase + tid] = s;
        bn_q[(size_t)bm * 256 + cBase + tid] = qq;
    }
}

// Finalize BN stats: one block per channel.
__global__ void k_stats(const float* __restrict__ bn_s, const float* __restrict__ bn_q,
                        const float* __restrict__ gamma, const float* __restrict__ beta,
                        float* __restrict__ scale, float* __restrict__ shift) {
    int c = blockIdx.x;
    int t = threadIdx.x;
    float s = 0.f, q = 0.f;
    for (int r = t; r < 2048; r += 256) {
        s += bn_s[(size_t)r * 256 + c];
        q += bn_q[(size_t)r * 256 + c];
    }
    __shared__ float ss[256], qq[256];
    ss[t] = s; qq[t] = q;
    __syncthreads();
    for (int off = 128; off; off >>= 1) {
        if (t < off) { ss[t] += ss[t + off]; qq[t] += qq[t + off]; }
        __syncthreads();
    }
    if (t == 0) {
        float mu  = ss[0] / 131072.f;
        float var = qq[0] / 131072.f - mu * mu;
        float sc = gamma[c] * rsqrtf(var + 1e-5f);
        scale[c] = sc;
        shift[c] = beta[c] - mu * sc;
    }
}

// Normalize + ReLU + 256->2 FC. One wave per row.
__global__ void k_out(const float* __restrict__ gf, const float* __restrict__ scale,
                      const float* __restrict__ shift, const float* __restrict__ Wfc,
                      const float* __restrict__ bfc, float* __restrict__ out) {
    int wid = threadIdx.x >> 6;
    int lane = threadIdx.x & 63;
    int i = blockIdx.x * 4 + wid;
    float4 gv = ((const float4*)(gf + (size_t)i * 256))[lane];
    int c0 = lane * 4;
    float4 sc = *(const float4*)(scale + c0);
    float4 sh = *(const float4*)(shift + c0);
    float y0 = fmaxf(gv.x * sc.x + sh.x, 0.f);
    float y1 = fmaxf(gv.y * sc.y + sh.y, 0.f);
    float y2 = fmaxf(gv.z * sc.z + sh.z, 0.f);
    float y3 = fmaxf(gv.w * sc.w + sh.w, 0.f);
    const float4* w = (const float4*)(Wfc + c0 * 2);
    float4 w0 = w[0], w1 = w[1];
    float p0 = y0 * w0.x + y1 * w0.z + y2 * w1.x + y3 * w1.z;
    float p1 = y0 * w0.y + y1 * w0.w + y2 * w1.y + y3 * w1.w;
    #pragma unroll
    for (int off = 32; off; off >>= 1) {
        p0 += __shfl_xor(p0, off);
        p1 += __shfl_xor(p1, off);
    }
    if (lane == 0) {
        out[(size_t)i * 2]     = p0 + bfc[0];
        out[(size_t)i * 2 + 1] = p1 + bfc[1];
    }
}

extern "C" void kernel_launch(void* const* d_in, const int* in_sizes, int n_in,
                              void* d_out, int out_size, void* d_ws, size_t ws_size,
                              hipStream_t stream) {
    const float* x          = (const float*)d_in[0];
    const unsigned char* mk = (const unsigned char*)d_in[1];
    const float* Wa  = (const float*)d_in[2];
    const float* ba  = (const float*)d_in[3];
    const float* Wv  = (const float*)d_in[4];
    const float* bv  = (const float*)d_in[5];
    const float* Wf  = (const float*)d_in[6];
    const float* bf  = (const float*)d_in[7];
    const float* gamma = (const float*)d_in[8];
    const float* beta  = (const float*)d_in[9];
    const float* Wfc = (const float*)d_in[10];
    const float* bfc = (const float*)d_in[11];
    float* out = (float*)d_out;

    char* ws = (char*)d_ws;
    float* sim   = (float*)(ws);
    float* Wvf   = (float*)(ws + (512u << 10));
    float* cf    = (float*)(ws + (1u << 20));
    int*   flag  = (int*)  (ws + (1u << 20) + 1024);
    float* scale = (float*)(ws + (1u << 20) + 2048);
    float* shift = (float*)(ws + (1u << 20) + 3072);
    float* bn_s  = (float*)(ws + (2u << 20));
    float* bn_q  = (float*)(ws + (4u << 20));
    float* gf    = (float*)(ws + (8u << 20));

    int n = in_sizes[1];  // NN

    k_detect<<<1, 256, 0, stream>>>(mk, n, flag);
    k_fold<<<513, 256, 0, stream>>>(Wv, Wf, bv, bf, Wvf, cf);
    k_sim<<<NN / 4, 256, 0, stream>>>(x, sim);
    k_gemm<<<dim3(2048, 2), 256, 0, stream>>>(x, mk, flag, Wa, Wf, Wvf, ba, cf, sim,
                                              gf, bn_s, bn_q);
    k_stats<<<256, 256, 0, stream>>>(bn_s, bn_q, gamma, beta, scale, shift);
    k_out<<<NN / 4, 256, 0, stream>>>(gf, scale, shift, Wfc, bfc, out);
}

// Round 2
// 464.935 us; speedup vs baseline: 2.2593x; 2.2593x over previous
//
#include <hip/hip_runtime.h>
#include <hip/hip_bf16.h>
#include <stdint.h>

#define NN 131072

typedef unsigned int uint;
typedef unsigned short ushort;
typedef __attribute__((ext_vector_type(8))) __bf16 bf16x8;
typedef __attribute__((ext_vector_type(2))) __bf16 bf16x2;
typedef __attribute__((ext_vector_type(4))) float f32x4;

// ---------------- ws layout (bytes) ----------------
// [0,512K)   sim (NN f32)
// [512K,1M)  Bt  (256 x 1024 bf16, col-major-by-output: Bt[c][k])
// 1M         cf (256 f32); 1M+1024 flag; 1M+2048 scale; 1M+3072 shift
// [2M,3M)    bn_s (1024*256 f32)
// [4M,5M)    bn_q
// [8M,+128M) graph_feats fp32

__device__ __forceinline__ ushort f2bf(float f) {
    uint u = __float_as_uint(f);
    u += 0x7FFF + ((u >> 16) & 1);
    return (ushort)(u >> 16);
}
__device__ __forceinline__ uint pk2(float a, float b) {
    bf16x2 t;
    t[0] = (__bf16)a;
    t[1] = (__bf16)b;
    return __builtin_bit_cast(uint, t);
}
__device__ __forceinline__ bool mask_val(const unsigned char* m8, int flag, int i) {
    return flag ? (m8[(size_t)i * 4] != 0) : (m8[i] != 0);
}

// Detect whether mask buffer is 1-byte bool (flag=0) or int32 (flag=1).
__global__ void k_detect(const unsigned char* m8, int n, int* flag) {
    __shared__ int cnt;
    if (threadIdx.x == 0) cnt = 0;
    __syncthreads();
    int local = 0;
    for (int i = threadIdx.x * 4 + 1; i < n; i += 1024) local += (m8[i] != 0) ? 1 : 0;
    if (local) atomicAdd(&cnt, local);
    __syncthreads();
    if (threadIdx.x == 0) *flag = (cnt == 0) ? 1 : 0;
}

// Build Bt[c][k] (bf16): k<256 -> W_a[k][c]; 256..511 -> W_f[k-256][c];
// 512..1023 -> (W_v @ W_f_bot)[k-512][c].  Block 1024 computes c_f.
__global__ void k_prep(const float* __restrict__ Wa, const float* __restrict__ Wf,
                       const float* __restrict__ Wv, const float* __restrict__ bv,
                       const float* __restrict__ bf_, ushort* __restrict__ Bt,
                       float* __restrict__ cf) {
    int c = threadIdx.x;
    int b = blockIdx.x;
    if (b < 256) {
        Bt[(size_t)c * 1024 + b] = f2bf(Wa[b * 256 + c]);
    } else if (b < 512) {
        Bt[(size_t)c * 1024 + b] = f2bf(Wf[(b - 256) * 256 + c]);
    } else if (b < 1024) {
        const float* wr = Wv + (b - 512) * 256;
        float acc = 0.f;
        for (int j = 0; j < 256; ++j) acc += wr[j] * Wf[(256 + j) * 256 + c];
        Bt[(size_t)c * 1024 + b] = f2bf(acc);
    } else {
        float acc = bf_[c];
        for (int j = 0; j < 256; ++j) acc += bv[j] * Wf[(256 + j) * 256 + c];
        cf[c] = acc;
    }
}

// Cosine similarity per row: one wave per row, 4 rows per block.
__global__ void k_sim(const float* __restrict__ x, float* __restrict__ sim) {
    int wid = threadIdx.x >> 6;
    int lane = threadIdx.x & 63;
    int i = blockIdx.x * 4 + wid;
    const float4* a = (const float4*)(x + (size_t)i * 2048 + 1024);
    const float4* v = (const float4*)(x + (size_t)i * 2048 + 1536);
    float4 a0 = a[lane], a1 = a[lane + 64];
    float4 v0 = v[lane], v1 = v[lane + 64];
    float dot = a0.x * v0.x + a0.y * v0.y + a0.z * v0.z + a0.w * v0.w
              + a1.x * v1.x + a1.y * v1.y + a1.z * v1.z + a1.w * v1.w;
    float na = a0.x * a0.x + a0.y * a0.y + a0.z * a0.z + a0.w * a0.w
             + a1.x * a1.x + a1.y * a1.y + a1.z * a1.z + a1.w * a1.w;
    float nv = v0.x * v0.x + v0.y * v0.y + v0.z * v0.z + v0.w * v0.w
             + v1.x * v1.x + v1.y * v1.y + v1.z * v1.z + v1.w * v1.w;
    #pragma unroll
    for (int off = 32; off; off >>= 1) {
        dot += __shfl_xor(dot, off);
        na  += __shfl_xor(na,  off);
        nv  += __shfl_xor(nv,  off);
    }
    if (lane == 0) {
        float denom = fmaxf(sqrtf(na) * sqrtf(nv), 1e-8f);
        sim[i] = dot / denom;
    }
}

// MFMA GEMM: 128 rows x 128 cols per block, K=1024 virtual, BK=64.
// A built on the fly from x (fp32 -> scale -> bf16); B from Bt (bf16, [c][k]).
// XOR-swizzled LDS (16B slots: slot ^= row&7). Writes gf + BN partials.
__global__ __launch_bounds__(256, 2) void k_mm(
    const float* __restrict__ x, const unsigned char* __restrict__ m8,
    const int* __restrict__ flagp, const ushort* __restrict__ Bt,
    const float* __restrict__ ba, const float* __restrict__ cf,
    const float* __restrict__ sim, float* __restrict__ gf,
    float* __restrict__ bn_s, float* __restrict__ bn_q)
{
    __shared__ bf16x8 As8[128 * 8];
    __shared__ bf16x8 Bs8[128 * 8];
    __shared__ float redS[128], redQ[128];

    const int tid = threadIdx.x;
    const int flag = *flagp;
    const int rowBase = blockIdx.x * 128;
    const int cBase = blockIdx.y * 128;

    // staging ids: 2 threads per row/col, 32 elems each
    const int sr = tid >> 1;
    const int sk32 = (tid & 1) * 32;   // element offset within BK=64
    const int sk4 = (tid & 1) * 4;     // 16B-slot offset
    const float* xrow = x + (size_t)(rowBase + sr) * 2048;
    const bool ms = mask_val(m8, flag, rowBase + sr);
    const float sims = sim[rowBase + sr];
    const ushort* brow = Bt + (size_t)(cBase + sr) * 1024 + sk32;

    // fragment ids
    const int lane = tid & 63;
    const int w = tid >> 6, wr = w >> 1, wc = w & 1;
    const int fr = lane & 15, fg = lane >> 4;

    f32x4 acc[4][4];
    #pragma unroll
    for (int m = 0; m < 4; ++m)
        #pragma unroll
        for (int n = 0; n < 4; ++n) acc[m][n] = (f32x4){0.f, 0.f, 0.f, 0.f};

    int4 pA[4], pB[4];

    auto loadA = [&](int st) {
        const int k0 = st * 64;
        const int seg = k0 >> 8;  // 0: a_in/mask, 1: a_in*sim/!mask, 2,3: v_in/!mask
        const float scl = (seg == 0) ? (ms ? 1.f : 0.f)
                         : (seg == 1) ? (ms ? 0.f : sims)
                                      : (ms ? 0.f : 1.f);
        const float4* src = (const float4*)(xrow + ((seg == 1) ? (k0 - 256) : k0) + sk32);
        #pragma unroll
        for (int s = 0; s < 4; ++s) {
            float4 u0 = src[2 * s], u1 = src[2 * s + 1];
            int4 p;
            p.x = pk2(u0.x * scl, u0.y * scl);
            p.y = pk2(u0.z * scl, u0.w * scl);
            p.z = pk2(u1.x * scl, u1.y * scl);
            p.w = pk2(u1.z * scl, u1.w * scl);
            pA[s] = p;
        }
    };
    auto loadB = [&](int st) {
        const int4* src = (const int4*)(brow + st * 64);
        #pragma unroll
        for (int s = 0; s < 4; ++s) pB[s] = src[s];
    };

    // step order: interleave seg0/seg1 so the a_in re-read L2-hits
    const int STEPS[16] = {0, 4, 1, 5, 2, 6, 3, 7, 8, 9, 10, 11, 12, 13, 14, 15};

    loadA(STEPS[0]);
    loadB(STEPS[0]);

    #pragma unroll
    for (int ii = 0; ii < 16; ++ii) {
        __syncthreads();  // previous tile's reads complete
        #pragma unroll
        for (int s = 0; s < 4; ++s) {
            As8[sr * 8 + ((sk4 + s) ^ (sr & 7))] = __builtin_bit_cast(bf16x8, pA[s]);
            Bs8[sr * 8 + ((sk4 + s) ^ (sr & 7))] = __builtin_bit_cast(bf16x8, pB[s]);
        }
        __syncthreads();  // tile ready
        if (ii < 15) { loadA(STEPS[ii + 1]); loadB(STEPS[ii + 1]); }
        #pragma unroll
        for (int kk = 0; kk < 2; ++kk) {
            bf16x8 af[4], bfv[4];
            #pragma unroll
            for (int m = 0; m < 4; ++m) {
                int r = wr * 64 + m * 16 + fr;
                af[m] = As8[r * 8 + ((kk * 4 + fg) ^ (r & 7))];
            }
            #pragma unroll
            for (int n = 0; n < 4; ++n) {
                int c = wc * 64 + n * 16 + fr;
                bfv[n] = Bs8[c * 8 + ((kk * 4 + fg) ^ (c & 7))];
            }
            #pragma unroll
            for (int m = 0; m < 4; ++m)
                #pragma unroll
                for (int n = 0; n < 4; ++n)
                    acc[m][n] = __builtin_amdgcn_mfma_f32_16x16x32_bf16(
                        af[m], bfv[n], acc[m][n], 0, 0, 0);
        }
    }

    // ---- epilogue: bias, gf store, BN partials ----
    __syncthreads();
    if (tid < 128) { redS[tid] = 0.f; redQ[tid] = 0.f; }
    __syncthreads();

    const int colLo = wc * 64 + fr;
    float baN[4], cfN[4];
    #pragma unroll
    for (int n = 0; n < 4; ++n) {
        baN[n] = ba[cBase + colLo + n * 16];
        cfN[n] = cf[cBase + colLo + n * 16];
    }
    float cs[4] = {0.f, 0.f, 0.f, 0.f}, cq[4] = {0.f, 0.f, 0.f, 0.f};
    #pragma unroll
    for (int m = 0; m < 4; ++m) {
        #pragma unroll
        for (int j = 0; j < 4; ++j) {
            int row = rowBase + wr * 64 + m * 16 + fg * 4 + j;
            bool mk = mask_val(m8, flag, row);
            float* grow = gf + (size_t)row * 256 + cBase;
            #pragma unroll
            for (int n = 0; n < 4; ++n) {
                float g = acc[m][n][j] + (mk ? baN[n] : cfN[n]);
                grow[colLo + n * 16] = g;
                cs[n] += g;
                cq[n] += g * g;
            }
        }
    }
    #pragma unroll
    for (int n = 0; n < 4; ++n) {
        atomicAdd(&redS[colLo + n * 16], cs[n]);
        atomicAdd(&redQ[colLo + n * 16], cq[n]);
    }
    __syncthreads();
    if (tid < 128) {
        bn_s[(size_t)blockIdx.x * 256 + cBase + tid] = redS[tid];
        bn_q[(size_t)blockIdx.x * 256 + cBase + tid] = redQ[tid];
    }
}

// Finalize BN stats: one block per channel, reduce 1024 row-block partials.
__global__ void k_stats(const float* __restrict__ bn_s, const float* __restrict__ bn_q,
                        const float* __restrict__ gamma, const float* __restrict__ beta,
                        float* __restrict__ scale, float* __restrict__ shift) {
    int c = blockIdx.x;
    int t = threadIdx.x;
    float s = 0.f, q = 0.f;
    for (int r = t; r < 1024; r += 256) {
        s += bn_s[(size_t)r * 256 + c];
        q += bn_q[(size_t)r * 256 + c];
    }
    __shared__ float ss[256], qq[256];
    ss[t] = s; qq[t] = q;
    __syncthreads();
    for (int off = 128; off; off >>= 1) {
        if (t < off) { ss[t] += ss[t + off]; qq[t] += qq[t + off]; }
        __syncthreads();
    }
    if (t == 0) {
        float mu  = ss[0] / 131072.f;
        float var = qq[0] / 131072.f - mu * mu;
        float sc = gamma[c] * rsqrtf(var + 1e-5f);
        scale[c] = sc;
        shift[c] = beta[c] - mu * sc;
    }
}

// Normalize + ReLU + 256->2 FC. One wave per row.
__global__ void k_out(const float* __restrict__ gf, const float* __restrict__ scale,
                      const float* __restrict__ shift, const float* __restrict__ Wfc,
                      const float* __restrict__ bfc, float* __restrict__ out) {
    int wid = threadIdx.x >> 6;
    int lane = threadIdx.x & 63;
    int i = blockIdx.x * 4 + wid;
    float4 gv = ((const float4*)(gf + (size_t)i * 256))[lane];
    int c0 = lane * 4;
    float4 sc = *(const float4*)(scale + c0);
    float4 sh = *(const float4*)(shift + c0);
    float y0 = fmaxf(gv.x * sc.x + sh.x, 0.f);
    float y1 = fmaxf(gv.y * sc.y + sh.y, 0.f);
    float y2 = fmaxf(gv.z * sc.z + sh.z, 0.f);
    float y3 = fmaxf(gv.w * sc.w + sh.w, 0.f);
    const float4* w = (const float4*)(Wfc + c0 * 2);
    float4 w0 = w[0], w1 = w[1];
    float p0 = y0 * w0.x + y1 * w0.z + y2 * w1.x + y3 * w1.z;
    float p1 = y0 * w0.y + y1 * w0.w + y2 * w1.y + y3 * w1.w;
    #pragma unroll
    for (int off = 32; off; off >>= 1) {
        p0 += __shfl_xor(p0, off);
        p1 += __shfl_xor(p1, off);
    }
    if (lane == 0) {
        out[(size_t)i * 2]     = p0 + bfc[0];
        out[(size_t)i * 2 + 1] = p1 + bfc[1];
    }
}

extern "C" void kernel_launch(void* const* d_in, const int* in_sizes, int n_in,
                              void* d_out, int out_size, void* d_ws, size_t ws_size,
                              hipStream_t stream) {
    const float* x          = (const float*)d_in[0];
    const unsigned char* mk = (const unsigned char*)d_in[1];
    const float* Wa  = (const float*)d_in[2];
    const float* ba  = (const float*)d_in[3];
    const float* Wv  = (const float*)d_in[4];
    const float* bv  = (const float*)d_in[5];
    const float* Wf  = (const float*)d_in[6];
    const float* bf  = (const float*)d_in[7];
    const float* gamma = (const float*)d_in[8];
    const float* beta  = (const float*)d_in[9];
    const float* Wfc = (const float*)d_in[10];
    const float* bfc = (const float*)d_in[11];
    float* out = (float*)d_out;

    char* ws = (char*)d_ws;
    float*  sim   = (float*)(ws);
    ushort* Bt    = (ushort*)(ws + (512u << 10));
    float*  cf    = (float*)(ws + (1u << 20));
    int*    flag  = (int*)  (ws + (1u << 20) + 1024);
    float*  scale = (float*)(ws + (1u << 20) + 2048);
    float*  shift = (float*)(ws + (1u << 20) + 3072);
    float*  bn_s  = (float*)(ws + (2u << 20));
    float*  bn_q  = (float*)(ws + (4u << 20));
    float*  gf    = (float*)(ws + (8u << 20));

    int n = in_sizes[1];  // NN

    k_detect<<<1, 256, 0, stream>>>(mk, n, flag);
    k_prep<<<1025, 256, 0, stream>>>(Wa, Wf, Wv, bv, bf, Bt, cf);
    k_sim<<<NN / 4, 256, 0, stream>>>(x, sim);
    k_mm<<<dim3(1024, 2), 256, 0, stream>>>(x, mk, flag, Bt, ba, cf, sim, gf, bn_s, bn_q);
    k_stats<<<256, 256, 0, stream>>>(bn_s, bn_q, gamma, beta, scale, shift);
    k_out<<<NN / 4, 256, 0, stream>>>(gf, scale, shift, Wfc, bfc, out);
}

// Round 3
// 371.110 us; speedup vs baseline: 2.8304x; 1.2528x over previous
//
#include <hip/hip_runtime.h>
#include <hip/hip_bf16.h>
#include <stdint.h>

#define NN 131072

typedef unsigned int uint;
typedef unsigned short ushort;
typedef __attribute__((ext_vector_type(8))) __bf16 bf16x8;
typedef __attribute__((ext_vector_type(2))) __bf16 bf16x2;
typedef __attribute__((ext_vector_type(4))) float f32x4;

// ---------------- ws layout (bytes) ----------------
// [512K,1M)  Bt  (256 x 1024 bf16: Bt[c][k])
// 1M         cf (256 f32); 1M+1024 flag; 1M+2048 scale; 1M+3072 shift
// [2M,3M)    bn_s (1024*256 f32)
// [4M,5M)    bn_q
// [8M,+64M)  graph_feats bf16 (NN*256)

__device__ __forceinline__ ushort f2bf(float f) {
    uint u = __float_as_uint(f);
    u += 0x7FFF + ((u >> 16) & 1);
    return (ushort)(u >> 16);
}
__device__ __forceinline__ uint pk2(float a, float b) {
    bf16x2 t;
    t[0] = (__bf16)a;
    t[1] = (__bf16)b;
    return __builtin_bit_cast(uint, t);
}
__device__ __forceinline__ bool mask_val(const unsigned char* m8, int flag, int i) {
    return flag ? (m8[(size_t)i * 4] != 0) : (m8[i] != 0);
}

// Detect whether mask buffer is 1-byte bool (flag=0) or int32 (flag=1).
__global__ void k_detect(const unsigned char* m8, int n, int* flag) {
    __shared__ int cnt;
    if (threadIdx.x == 0) cnt = 0;
    __syncthreads();
    int local = 0;
    for (int i = threadIdx.x * 4 + 1; i < n; i += 1024) local += (m8[i] != 0) ? 1 : 0;
    if (local) atomicAdd(&cnt, local);
    __syncthreads();
    if (threadIdx.x == 0) *flag = (cnt == 0) ? 1 : 0;
}

// Build Bt[c][k] (bf16): k<256 -> W_a[k][c]; 256..511 -> W_f[k-256][c];
// 512..1023 -> (W_v @ W_f_bot)[k-512][c].  Block 1024 computes c_f.
__global__ void k_prep(const float* __restrict__ Wa, const float* __restrict__ Wf,
                       const float* __restrict__ Wv, const float* __restrict__ bv,
                       const float* __restrict__ bf_, ushort* __restrict__ Bt,
                       float* __restrict__ cf) {
    int c = threadIdx.x;
    int b = blockIdx.x;
    if (b < 256) {
        Bt[(size_t)c * 1024 + b] = f2bf(Wa[b * 256 + c]);
    } else if (b < 512) {
        Bt[(size_t)c * 1024 + b] = f2bf(Wf[(b - 256) * 256 + c]);
    } else if (b < 1024) {
        const float* wr = Wv + (b - 512) * 256;
        float acc = 0.f;
        for (int j = 0; j < 256; ++j) acc += wr[j] * Wf[(256 + j) * 256 + c];
        Bt[(size_t)c * 1024 + b] = f2bf(acc);
    } else {
        float acc = bf_[c];
        for (int j = 0; j < 256; ++j) acc += bv[j] * Wf[(256 + j) * 256 + c];
        cf[c] = acc;
    }
}

// Fused: cosine-sim prologue + MFMA GEMM (BM=128 rows, BN=256 = all cols,
// K=1024 virtual, BK=64, 8 waves in 2x4). Writes bf16 gf + BN partials.
__global__ __launch_bounds__(512, 4) void k_main(
    const float* __restrict__ x, const unsigned char* __restrict__ m8,
    const int* __restrict__ flagp, const ushort* __restrict__ Bt,
    const float* __restrict__ ba, const float* __restrict__ cf,
    ushort* __restrict__ gf, float* __restrict__ bn_s, float* __restrict__ bn_q)
{
    __shared__ bf16x8 As8[128 * 8];           // 16 KB
    __shared__ bf16x8 Bs8[256 * 8];           // 32 KB
    __shared__ float simS[128];
    __shared__ unsigned char maskS[128];
    __shared__ float redS[256], redQ[256];

    const int tid = threadIdx.x;
    const int flag = *flagp;
    const int rowBase = blockIdx.x * 128;

    // ---- phase 1: cosine sim for this block's 128 rows (4 lanes/row) ----
    {
        int r = tid >> 2, c = tid & 3;
        size_t base = (size_t)(rowBase + r) * 2048;
        const float4* ap = (const float4*)(x + base + 1024 + c * 128);
        const float4* vp = (const float4*)(x + base + 1536 + c * 128);
        float dot = 0.f, na = 0.f, nv = 0.f;
        #pragma unroll 4
        for (int j = 0; j < 32; ++j) {
            float4 a = ap[j], v = vp[j];
            dot += a.x * v.x + a.y * v.y + a.z * v.z + a.w * v.w;
            na  += a.x * a.x + a.y * a.y + a.z * a.z + a.w * a.w;
            nv  += v.x * v.x + v.y * v.y + v.z * v.z + v.w * v.w;
        }
        dot += __shfl_xor(dot, 1); na += __shfl_xor(na, 1); nv += __shfl_xor(nv, 1);
        dot += __shfl_xor(dot, 2); na += __shfl_xor(na, 2); nv += __shfl_xor(nv, 2);
        if (c == 0) {
            simS[r]  = dot / fmaxf(sqrtf(na) * sqrtf(nv), 1e-8f);
            maskS[r] = mask_val(m8, flag, rowBase + r) ? 1 : 0;
        }
    }
    __syncthreads();

    // ---- phase 2: GEMM ----
    // staging ids: A: 4 threads/row, 16 floats each; B: 2 threads/col, 32 bf16 each
    const int sr = tid >> 2, sk = tid & 3;
    const int br = tid >> 1, bs = tid & 1;
    const float* xrow = x + (size_t)(rowBase + sr) * 2048;
    const ushort* brow = Bt + (size_t)br * 1024 + bs * 32;
    const int msk_s = maskS[sr];
    const float sims = simS[sr];
    const float scl0 = msk_s ? 1.f : 0.f;
    const float scl1 = msk_s ? 0.f : sims;
    const float scl2 = msk_s ? 0.f : 1.f;

    // fragment ids (8 waves: 2 row-groups x 4 col-groups)
    const int lane = tid & 63;
    const int w = tid >> 6, wr = w >> 2, wc = w & 3;
    const int fr = lane & 15, fg = lane >> 4;

    f32x4 acc[4][4];
    #pragma unroll
    for (int m = 0; m < 4; ++m)
        #pragma unroll
        for (int n = 0; n < 4; ++n) acc[m][n] = (f32x4){0.f, 0.f, 0.f, 0.f};

    int4 pA[2], pB[4];

    auto loadA = [&](int st) {
        const int k0 = st * 64;
        const float scl = (st < 4) ? scl0 : (st < 8) ? scl1 : scl2;
        const float4* src = (const float4*)(xrow + ((st < 8) ? (k0 & 255) : k0) + sk * 16);
        #pragma unroll
        for (int s = 0; s < 2; ++s) {
            float4 u0 = src[2 * s], u1 = src[2 * s + 1];
            int4 p;
            p.x = pk2(u0.x * scl, u0.y * scl);
            p.y = pk2(u0.z * scl, u0.w * scl);
            p.z = pk2(u1.x * scl, u1.y * scl);
            p.w = pk2(u1.z * scl, u1.w * scl);
            pA[s] = p;
        }
    };
    auto loadB = [&](int st) {
        const int4* src = (const int4*)(brow + st * 64);
        #pragma unroll
        for (int s = 0; s < 4; ++s) pB[s] = src[s];
    };

    // step order: interleave seg0/seg1 so the a_in re-read L2-hits
    const int STEPS[16] = {0, 4, 1, 5, 2, 6, 3, 7, 8, 9, 10, 11, 12, 13, 14, 15};

    loadA(STEPS[0]);
    loadB(STEPS[0]);

    #pragma unroll
    for (int ii = 0; ii < 16; ++ii) {
        __syncthreads();
        #pragma unroll
        for (int s = 0; s < 2; ++s)
            As8[sr * 8 + ((sk * 2 + s) ^ (sr & 7))] = __builtin_bit_cast(bf16x8, pA[s]);
        #pragma unroll
        for (int s = 0; s < 4; ++s)
            Bs8[br * 8 + ((bs * 4 + s) ^ (br & 7))] = __builtin_bit_cast(bf16x8, pB[s]);
        __syncthreads();
        if (ii < 15) { loadA(STEPS[ii + 1]); loadB(STEPS[ii + 1]); }
        #pragma unroll
        for (int kk = 0; kk < 2; ++kk) {
            bf16x8 af[4], bfv[4];
            #pragma unroll
            for (int m = 0; m < 4; ++m) {
                int r = wr * 64 + m * 16 + fr;
                af[m] = As8[r * 8 + ((kk * 4 + fg) ^ (r & 7))];
            }
            #pragma unroll
            for (int n = 0; n < 4; ++n) {
                int c = wc * 64 + n * 16 + fr;
                bfv[n] = Bs8[c * 8 + ((kk * 4 + fg) ^ (c & 7))];
            }
            #pragma unroll
            for (int m = 0; m < 4; ++m)
                #pragma unroll
                for (int n = 0; n < 4; ++n)
                    acc[m][n] = __builtin_amdgcn_mfma_f32_16x16x32_bf16(
                        af[m], bfv[n], acc[m][n], 0, 0, 0);
        }
    }

    // ---- epilogue: bias, bf16 gf store, BN partials ----
    __syncthreads();
    if (tid < 256) { redS[tid] = 0.f; redQ[tid] = 0.f; }
    __syncthreads();

    const int colLo = wc * 64 + fr;
    float baN[4], cfN[4];
    #pragma unroll
    for (int n = 0; n < 4; ++n) {
        baN[n] = ba[colLo + n * 16];
        cfN[n] = cf[colLo + n * 16];
    }
    float cs[4] = {0.f, 0.f, 0.f, 0.f}, cq[4] = {0.f, 0.f, 0.f, 0.f};
    #pragma unroll
    for (int m = 0; m < 4; ++m) {
        #pragma unroll
        for (int j = 0; j < 4; ++j) {
            int rloc = wr * 64 + m * 16 + fg * 4 + j;
            int mk = maskS[rloc];
            ushort* grow = gf + (size_t)(rowBase + rloc) * 256;
            #pragma unroll
            for (int n = 0; n < 4; ++n) {
                float g = acc[m][n][j] + (mk ? baN[n] : cfN[n]);
                grow[colLo + n * 16] = f2bf(g);
                cs[n] += g;
                cq[n] += g * g;
            }
        }
    }
    #pragma unroll
    for (int n = 0; n < 4; ++n) {
        atomicAdd(&redS[colLo + n * 16], cs[n]);
        atomicAdd(&redQ[colLo + n * 16], cq[n]);
    }
    __syncthreads();
    if (tid < 256) {
        bn_s[(size_t)blockIdx.x * 256 + tid] = redS[tid];
        bn_q[(size_t)blockIdx.x * 256 + tid] = redQ[tid];
    }
}

// Finalize BN stats: one block per channel, reduce 1024 row-block partials.
__global__ void k_stats(const float* __restrict__ bn_s, const float* __restrict__ bn_q,
                        const float* __restrict__ gamma, const float* __restrict__ beta,
                        float* __restrict__ scale, float* __restrict__ shift) {
    int c = blockIdx.x;
    int t = threadIdx.x;
    float s = 0.f, q = 0.f;
    for (int r = t; r < 1024; r += 256) {
        s += bn_s[(size_t)r * 256 + c];
        q += bn_q[(size_t)r * 256 + c];
    }
    __shared__ float ss[256], qq[256];
    ss[t] = s; qq[t] = q;
    __syncthreads();
    for (int off = 128; off; off >>= 1) {
        if (t < off) { ss[t] += ss[t + off]; qq[t] += qq[t + off]; }
        __syncthreads();
    }
    if (t == 0) {
        float mu  = ss[0] / 131072.f;
        float var = qq[0] / 131072.f - mu * mu;
        float sc = gamma[c] * rsqrtf(var + 1e-5f);
        scale[c] = sc;
        shift[c] = beta[c] - mu * sc;
    }
}

// Normalize + ReLU + 256->2 FC. One wave per row, bf16 gf input.
__global__ void k_out(const ushort* __restrict__ gf, const float* __restrict__ scale,
                      const float* __restrict__ shift, const float* __restrict__ Wfc,
                      const float* __restrict__ bfc, float* __restrict__ out) {
    int wid = threadIdx.x >> 6;
    int lane = threadIdx.x & 63;
    int i = blockIdx.x * 4 + wid;
    uint2 gv = ((const uint2*)(gf + (size_t)i * 256))[lane];
    float g0 = __uint_as_float(gv.x << 16);
    float g1 = __uint_as_float(gv.x & 0xFFFF0000u);
    float g2 = __uint_as_float(gv.y << 16);
    float g3 = __uint_as_float(gv.y & 0xFFFF0000u);
    int c0 = lane * 4;
    float4 sc = *(const float4*)(scale + c0);
    float4 sh = *(const float4*)(shift + c0);
    float y0 = fmaxf(g0 * sc.x + sh.x, 0.f);
    float y1 = fmaxf(g1 * sc.y + sh.y, 0.f);
    float y2 = fmaxf(g2 * sc.z + sh.z, 0.f);
    float y3 = fmaxf(g3 * sc.w + sh.w, 0.f);
    const float4* w = (const float4*)(Wfc + c0 * 2);
    float4 w0 = w[0], w1 = w[1];
    float p0 = y0 * w0.x + y1 * w0.z + y2 * w1.x + y3 * w1.z;
    float p1 = y0 * w0.y + y1 * w0.w + y2 * w1.y + y3 * w1.w;
    #pragma unroll
    for (int off = 32; off; off >>= 1) {
        p0 += __shfl_xor(p0, off);
        p1 += __shfl_xor(p1, off);
    }
    if (lane == 0) {
        out[(size_t)i * 2]     = p0 + bfc[0];
        out[(size_t)i * 2 + 1] = p1 + bfc[1];
    }
}

extern "C" void kernel_launch(void* const* d_in, const int* in_sizes, int n_in,
                              void* d_out, int out_size, void* d_ws, size_t ws_size,
                              hipStream_t stream) {
    const float* x          = (const float*)d_in[0];
    const unsigned char* mk = (const unsigned char*)d_in[1];
    const float* Wa  = (const float*)d_in[2];
    const float* ba  = (const float*)d_in[3];
    const float* Wv  = (const float*)d_in[4];
    const float* bv  = (const float*)d_in[5];
    const float* Wf  = (const float*)d_in[6];
    const float* bf  = (const float*)d_in[7];
    const float* gamma = (const float*)d_in[8];
    const float* beta  = (const float*)d_in[9];
    const float* Wfc = (const float*)d_in[10];
    const float* bfc = (const float*)d_in[11];
    float* out = (float*)d_out;

    char* ws = (char*)d_ws;
    ushort* Bt    = (ushort*)(ws + (512u << 10));
    float*  cf    = (float*)(ws + (1u << 20));
    int*    flag  = (int*)  (ws + (1u << 20) + 1024);
    float*  scale = (float*)(ws + (1u << 20) + 2048);
    float*  shift = (float*)(ws + (1u << 20) + 3072);
    float*  bn_s  = (float*)(ws + (2u << 20));
    float*  bn_q  = (float*)(ws + (4u << 20));
    ushort* gf    = (ushort*)(ws + (8u << 20));

    int n = in_sizes[1];  // NN

    k_detect<<<1, 256, 0, stream>>>(mk, n, flag);
    k_prep<<<1025, 256, 0, stream>>>(Wa, Wf, Wv, bv, bf, Bt, cf);
    k_main<<<1024, 512, 0, stream>>>(x, mk, flag, Bt, ba, cf, gf, bn_s, bn_q);
    k_stats<<<256, 256, 0, stream>>>(bn_s, bn_q, gamma, beta, scale, shift);
    k_out<<<NN / 4, 256, 0, stream>>>(gf, scale, shift, Wfc, bfc, out);
}